// Round 2
// baseline (936.636 us; speedup 1.0000x reference)
//
#include <hip/hip_runtime.h>

typedef float v2f __attribute__((ext_vector_type(2)));

#define B_ 64
#define N_ 4096
#define C_ 128
#define W_ 64
#define WIN_ 4033
#define CG 16        // channels per block
#define CHUNK 256    // n per staged chunk
#define STAGE 336    // CHUNK + 80 lookahead (covers window reads to +328)
#define SROW 357     // skewed LDS row stride in f2: odd, ==5 mod 16 -> conflict-min
#define NH 2
#define HALF_N 2048

__device__ __forceinline__ int skew(int u) { return u + (u >> 4); }

// Depthwise sliding correlation, both complex components packed in v2f.
// Grid: 32 b-pairs x 8 cgroups x 2 n-halves = 512 blocks, 256 threads.
// Thread: (bsel, np, tg, cl); T=32 acc, 8-n micro-steps, 40-f2 reg window.
// Partials atomically accumulated into facc[b][c][t] (f2 as 2 floats).
__global__ __launch_bounds__(256, 2) void conv_main(
    const v2f* __restrict__ x2,    // [B][N][C] f2
    const float* __restrict__ wr,  // [C][WIN]
    const float* __restrict__ wi,  // [C][WIN]
    float* __restrict__ facc) {    // [B][C][64] f2 -> 2 floats, pre-zeroed
  __shared__ __attribute__((aligned(16))) v2f wsh[CG * SROW];  // 45.7 KB

  int tid = threadIdx.x;
  int bid = blockIdx.x;
  int half = bid & 1;
  int cg = (bid >> 1) & 7;   // XCD-friendly: adjacent bids spread halves/cgroups
  int bp = bid >> 4;
  int cl = tid & 15;
  int tg = (tid >> 4) & 1;
  int np = (tid >> 5) & 3;
  int bsel = tid >> 7;
  int b = bp * 2 + bsel;
  int cbase = cg * CG;
  int c = cbase + cl;
  int t0 = tg * 32;
  int halfstart = half * HALF_N;
  int nthr = np * 64;  // thread n-base within chunk

  v2f acc[32];
#pragma unroll
  for (int i = 0; i < 32; i++) acc[i] = (v2f){0.f, 0.f};

  const v2f* xg = x2 + ((size_t)b * N_ + halfstart) * C_ + c;
  const v2f* wrow = wsh + cl * SROW;

  v2f win[40];
  v2f xw[3][8];

  for (int ch = 0; ch < 8; ++ch) {
    int n0 = halfstart + ch * CHUNK;  // global kk base of staged region
    int ncb = ch * CHUNK + nthr;      // half-local base of thread's n range

    // preload first two x micro-blocks of this chunk (independent of barriers)
#pragma unroll
    for (int j = 0; j < 8; j++) xw[0][j] = xg[(size_t)(ncb + j) * C_];
#pragma unroll
    for (int j = 0; j < 8; j++) xw[1][j] = xg[(size_t)(ncb + 8 + j) * C_];

    __syncthreads();  // all reads of previous staged chunk complete

    // ---- stage 16ch x 336 f2, interleaved + zero-padded from raw wr/wi ----
#pragma unroll
    for (int cc = 0; cc < CG; ++cc) {
      const float* wrp = wr + (size_t)(cbase + cc) * WIN_;
      const float* wip = wi + (size_t)(cbase + cc) * WIN_;
      {
        int u = tid;
        int k = n0 + u - 64;
        bool ok = (unsigned)k < (unsigned)WIN_;
        v2f v;
        v.x = ok ? wrp[k] : 0.f;
        v.y = ok ? wip[k] : 0.f;
        wsh[cc * SROW + skew(u)] = v;
      }
      if (tid < STAGE - 256) {
        int u = tid + 256;
        int k = n0 + u - 64;
        bool ok = (unsigned)k < (unsigned)WIN_;
        v2f v;
        v.x = ok ? wrp[k] : 0.f;
        v.y = ok ? wip[k] : 0.f;
        wsh[cc * SROW + skew(u)] = v;
      }
    }
    __syncthreads();

    // ---- init 40-f2 register window: win[m] = staged(nthr + 33 - t0 + m) ----
#pragma unroll
    for (int m = 0; m < 40; m++) win[m] = wrow[skew(nthr + 33 - t0 + m)];

    // ---- 8 micro-blocks of 8 n ----
#pragma unroll
    for (int blk = 0; blk < 8; ++blk) {
      int nbc = nthr + blk * 8;
      if (blk < 6) {  // prefetch x for micro-block blk+2
#pragma unroll
        for (int j = 0; j < 8; j++)
          xw[(blk + 2) % 3][j] = xg[(size_t)(ch * CHUNK + nbc + 16 + j) * C_];
      }
      const v2f* xv = xw[blk % 3];
#pragma unroll
      for (int j = 0; j < 8; j++) {
#pragma unroll
        for (int i = 0; i < 32; i++) {
          acc[i] = __builtin_elementwise_fma(xv[j], win[31 + j - i], acc[i]);
        }
      }
      if (blk < 7) {  // slide window by 8 (renamed by full unroll), read 8 new
#pragma unroll
        for (int m = 0; m < 32; m++) win[m] = win[m + 8];
#pragma unroll
        for (int r = 0; r < 8; r++)
          win[32 + r] = wrow[skew(nbc + 73 - t0 + r)];
      }
    }
  }

  // ---- epilogue: atomic-accumulate partials (np x half x ... = 8 writers) ----
  float* fp = facc + (((size_t)b * C_ + c) * 64 + t0) * 2;
#pragma unroll
  for (int i = 0; i < 32; i++) {
    atomicAdd(fp + 2 * i + 0, acc[i].x);
    atomicAdd(fp + 2 * i + 1, acc[i].y);
  }
}

// Nonlinearity + output filter: facc -> pre[b][c][2]. 2048 blocks x 256 thr.
__global__ void nonlin_out(const float* __restrict__ faccf,
                           const float* __restrict__ Anl,
                           const float* __restrict__ Wcm,
                           const float* __restrict__ wor,
                           const float* __restrict__ woi,
                           float* __restrict__ pre) {
  int tid = threadIdx.x;
  int p = tid >> 6;
  int t = tid & 63;
  int idx = blockIdx.x * 4 + p;
  int b = idx >> 7;
  int c = idx & 127;
  const v2f* f2 = (const v2f*)faccf;
  v2f f = f2[((size_t)b * C_ + c) * 64 + t];
  float a00 = Anl[c * 4 + 0], a01 = Anl[c * 4 + 1];
  float a10 = Anl[c * 4 + 2], a11 = Anl[c * 4 + 3];
  float ur = a00 * f.x + a01 * f.y;
  float ui = a10 * f.x + a11 * f.y;
  float amp = ur * ur + ui * ui;
  ur *= amp;
  ui *= amp;
  float vr = Wcm[0] * ur + Wcm[1] * ui;
  float vi = Wcm[2] * ur + Wcm[3] * ui;
  float or_ = vr * wor[c * 64 + t];
  float oi_ = vi * woi[c * 64 + t];
#pragma unroll
  for (int d = 32; d > 0; d >>= 1) {
    or_ += __shfl_down(or_, d, 64);
    oi_ += __shfl_down(oi_, d, 64);
  }
  if (t == 0) {
    pre[((size_t)b * C_ + c) * 2 + 0] = or_;
    pre[((size_t)b * C_ + c) * 2 + 1] = oi_;
  }
}

// Train-mode BatchNorm1d over (B, comp) per channel. 128 blocks x 128 thr.
__global__ void bn_kernel(const float* __restrict__ pre, const float* __restrict__ gamma,
                          const float* __restrict__ beta, float* __restrict__ out) {
  int c = blockIdx.x, tid = threadIdx.x;
  int b = tid >> 1, comp = tid & 1;
  float v = pre[((size_t)b * C_ + c) * 2 + comp];
  float s = v, s2 = v * v;
#pragma unroll
  for (int d = 32; d > 0; d >>= 1) {
    s += __shfl_down(s, d, 64);
    s2 += __shfl_down(s2, d, 64);
  }
  __shared__ float red[4];
  if ((tid & 63) == 0) {
    red[(tid >> 6) * 2 + 0] = s;
    red[(tid >> 6) * 2 + 1] = s2;
  }
  __syncthreads();
  float sum = red[0] + red[2], sumsq = red[1] + red[3];
  float mean = sum * 0.0078125f;
  float var = sumsq * 0.0078125f - mean * mean;
  float inv = rsqrtf(var + 1e-5f);
  out[((size_t)b * C_ + c) * 2 + comp] = (v - mean) * inv * gamma[c] + beta[c];
}

extern "C" void kernel_launch(void* const* d_in, const int* in_sizes, int n_in,
                              void* d_out, int out_size, void* d_ws, size_t ws_size,
                              hipStream_t stream) {
  (void)in_sizes; (void)n_in; (void)out_size; (void)ws_size;
  const float* x   = (const float*)d_in[0];
  const float* wir = (const float*)d_in[1];
  const float* wii = (const float*)d_in[2];
  const float* Anl = (const float*)d_in[3];
  const float* Wcm = (const float*)d_in[4];
  const float* wrr = (const float*)d_in[5];
  const float* wri = (const float*)d_in[6];
  const float* gam = (const float*)d_in[7];
  const float* bet = (const float*)d_in[8];

  float* facc = (float*)d_ws;                         // 4.19 MB
  float* pre  = facc + (size_t)B_ * C_ * 64 * 2;      // 64 KB

  hipMemsetAsync(facc, 0, (size_t)B_ * C_ * 64 * 2 * sizeof(float), stream);
  conv_main<<<32 * 8 * NH, 256, 0, stream>>>((const v2f*)x, wir, wii, facc);
  nonlin_out<<<(B_ * C_) / 4, 256, 0, stream>>>(facc, Anl, Wcm, wrr, wri, pre);
  bn_kernel<<<C_, 128, 0, stream>>>(pre, gam, bet, (float*)d_out);
}

// Round 3
// 570.699 us; speedup vs baseline: 1.6412x; 1.6412x over previous
//
#include <hip/hip_runtime.h>

typedef float v2f __attribute__((ext_vector_type(2)));

#define B_ 64
#define N_ 4096
#define C_ 128
#define W_ 64
#define WIN_ 4033
#define CG 16        // channels per block
#define CHUNK 256    // n per staged chunk
#define STAGE 336    // CHUNK + 80 lookahead (window reads reach +319)
#define SROW 337     // ODD LDS row stride in f2 -> cl spreads over all 16 bank-pairs
#define HALF_N 2048

// Depthwise sliding correlation, complex pair packed in v2f. R1 structure
// (88 VGPR, no spill) + odd stride (conflict fix) + N-half split (occupancy).
// Grid: 8 cg x 2 half x 64 b = 1024 blocks, 256 threads.
// Thread: cl=(tid>>2)&15 channel, t0g=tid&3 -> t0=16*t0g, np=tid>>6 n-quarter.
__global__ __launch_bounds__(256, 3) void conv_main(
    const v2f* __restrict__ x2,    // [B][N][C] f2
    const float* __restrict__ wr,  // [C][WIN]
    const float* __restrict__ wi,  // [C][WIN]
    float* __restrict__ facc) {    // [B][C][64][2], pre-zeroed, atomic-merged
  __shared__ __attribute__((aligned(16))) v2f wsh[CG * SROW];  // 43.1 KB

  int tid = threadIdx.x;
  int bid = blockIdx.x;
  int cg = bid & 7;            // XCD-friendly: consecutive bids spread cg
  int half = (bid >> 3) & 1;
  int bb = bid >> 4;
  int cbase = cg * CG;
  int cl = (tid >> 2) & 15;
  int t0g = tid & 3;
  int np = tid >> 6;
  int t0 = t0g << 4;
  int nbase = np << 6;
  int halfstart = half * HALF_N;

  v2f zero = {0.f, 0.f};
  v2f acc[16];
#pragma unroll
  for (int i = 0; i < 16; i++) acc[i] = zero;

  const v2f* xg = x2 + ((size_t)bb * N_ + halfstart) * C_ + cbase + cl;
  const v2f* wrow = wsh + cl * SROW;

  for (int n0 = 0; n0 < HALF_N; n0 += CHUNK) {  // half-local chunk base
    // ---- stage 16ch x 336 f2 (interleaved + zero-padded from raw wr/wi) ----
    {
      int kb = halfstart + n0 - 64;  // real k of staged u=0
#pragma unroll
      for (int cc = 0; cc < CG; ++cc) {
        const float* wrp = wr + (size_t)(cbase + cc) * WIN_;
        const float* wip = wi + (size_t)(cbase + cc) * WIN_;
        {
          int u = tid;
          int k = kb + u;
          bool ok = (unsigned)k < (unsigned)WIN_;
          v2f v;
          v.x = ok ? wrp[k] : 0.f;
          v.y = ok ? wip[k] : 0.f;
          wsh[cc * SROW + u] = v;
        }
        if (tid < STAGE - 256) {
          int u = tid + 256;
          int k = kb + u;
          bool ok = (unsigned)k < (unsigned)WIN_;
          v2f v;
          v.x = ok ? wrp[k] : 0.f;
          v.y = ok ? wip[k] : 0.f;
          wsh[cc * SROW + u] = v;
        }
      }
    }
    __syncthreads();

    // ---- compute: thread covers n in [n0+nbase, +64), t in [t0, t0+16) ----
    v2f wA[16], wB[16], xA[16], xB[16];
#pragma unroll
    for (int m = 0; m < 16; m++) wA[m] = wrow[nbase + 48 - t0 + m];
#pragma unroll
    for (int j = 0; j < 16; j++) xA[j] = xg[(size_t)(n0 + nbase + j) * C_];

    auto pref = [&](int nb, v2f* xv) {
#pragma unroll
      for (int j = 0; j < 16; j++) xv[j] = xg[(size_t)(n0 + nb + j) * C_];
    };
    // invariant: wold[m] = staged[nb+64-t0-16+m]; loads wnew[j] = staged[nb+64-t0+j]
    auto do16 = [&](int nb, const v2f* xv, const v2f* wold, v2f* wnew) {
#pragma unroll
      for (int j = 0; j < 16; j++) wnew[j] = wrow[nb + 64 - t0 + j];
#pragma unroll
      for (int j = 0; j < 16; j++) {
#pragma unroll
        for (int i = 0; i < 16; i++) {
          int e = j - i;
          v2f wv = (e < 0) ? wold[16 + e] : wnew[e];
          acc[i] = __builtin_elementwise_fma(xv[j], wv, acc[i]);
        }
      }
    };

    pref(nbase + 16, xB);
    do16(nbase + 0, xA, wA, wB);
    pref(nbase + 32, xA);
    do16(nbase + 16, xB, wB, wA);
    pref(nbase + 48, xB);
    do16(nbase + 32, xA, wA, wB);
    do16(nbase + 48, xB, wB, wA);
    __syncthreads();
  }

  // ---- reduce n-quarters in LDS (stride 65: conflict-free), atomic-merge ----
  v2f* fpart = wsh;  // [np][cl] rows of 65, 4*16*65 f2 = 33.3 KB <= wsh
#pragma unroll
  for (int i = 0; i < 16; i++) fpart[(np * CG + cl) * 65 + t0 + i] = acc[i];
  __syncthreads();

  int cl2 = tid & 15;
  int tq = tid >> 4;  // 0..15
  float* fp = facc + ((size_t)bb * C_ + cbase + cl2) * 128;
#pragma unroll
  for (int q = 0; q < 4; q++) {
    int t = tq + (q << 4);
    v2f f = fpart[(0 * CG + cl2) * 65 + t] + fpart[(1 * CG + cl2) * 65 + t] +
            fpart[(2 * CG + cl2) * 65 + t] + fpart[(3 * CG + cl2) * 65 + t];
    atomicAdd(fp + 2 * t + 0, f.x);
    atomicAdd(fp + 2 * t + 1, f.y);
  }
}

// Nonlinearity + output filter: facc -> pre[b][c][2]. 2048 blocks x 256 thr.
__global__ void nonlin_out(const float* __restrict__ faccf,
                           const float* __restrict__ Anl,
                           const float* __restrict__ Wcm,
                           const float* __restrict__ wor,
                           const float* __restrict__ woi,
                           float* __restrict__ pre) {
  int tid = threadIdx.x;
  int p = tid >> 6;
  int t = tid & 63;
  int idx = blockIdx.x * 4 + p;
  int b = idx >> 7;
  int c = idx & 127;
  const v2f* f2 = (const v2f*)faccf;
  v2f f = f2[((size_t)b * C_ + c) * 64 + t];
  float a00 = Anl[c * 4 + 0], a01 = Anl[c * 4 + 1];
  float a10 = Anl[c * 4 + 2], a11 = Anl[c * 4 + 3];
  float ur = a00 * f.x + a01 * f.y;
  float ui = a10 * f.x + a11 * f.y;
  float amp = ur * ur + ui * ui;
  ur *= amp;
  ui *= amp;
  float vr = Wcm[0] * ur + Wcm[1] * ui;
  float vi = Wcm[2] * ur + Wcm[3] * ui;
  float or_ = vr * wor[c * 64 + t];
  float oi_ = vi * woi[c * 64 + t];
#pragma unroll
  for (int d = 32; d > 0; d >>= 1) {
    or_ += __shfl_down(or_, d, 64);
    oi_ += __shfl_down(oi_, d, 64);
  }
  if (t == 0) {
    pre[((size_t)b * C_ + c) * 2 + 0] = or_;
    pre[((size_t)b * C_ + c) * 2 + 1] = oi_;
  }
}

// Train-mode BatchNorm1d over (B, comp) per channel. 128 blocks x 128 thr.
__global__ void bn_kernel(const float* __restrict__ pre, const float* __restrict__ gamma,
                          const float* __restrict__ beta, float* __restrict__ out) {
  int c = blockIdx.x, tid = threadIdx.x;
  int b = tid >> 1, comp = tid & 1;
  float v = pre[((size_t)b * C_ + c) * 2 + comp];
  float s = v, s2 = v * v;
#pragma unroll
  for (int d = 32; d > 0; d >>= 1) {
    s += __shfl_down(s, d, 64);
    s2 += __shfl_down(s2, d, 64);
  }
  __shared__ float red[4];
  if ((tid & 63) == 0) {
    red[(tid >> 6) * 2 + 0] = s;
    red[(tid >> 6) * 2 + 1] = s2;
  }
  __syncthreads();
  float sum = red[0] + red[2], sumsq = red[1] + red[3];
  float mean = sum * 0.0078125f;
  float var = sumsq * 0.0078125f - mean * mean;
  float inv = rsqrtf(var + 1e-5f);
  out[((size_t)b * C_ + c) * 2 + comp] = (v - mean) * inv * gamma[c] + beta[c];
}

extern "C" void kernel_launch(void* const* d_in, const int* in_sizes, int n_in,
                              void* d_out, int out_size, void* d_ws, size_t ws_size,
                              hipStream_t stream) {
  (void)in_sizes; (void)n_in; (void)out_size; (void)ws_size;
  const float* x   = (const float*)d_in[0];
  const float* wir = (const float*)d_in[1];
  const float* wii = (const float*)d_in[2];
  const float* Anl = (const float*)d_in[3];
  const float* Wcm = (const float*)d_in[4];
  const float* wrr = (const float*)d_in[5];
  const float* wri = (const float*)d_in[6];
  const float* gam = (const float*)d_in[7];
  const float* bet = (const float*)d_in[8];

  float* facc = (float*)d_ws;                     // 4.19 MB
  float* pre  = facc + (size_t)B_ * C_ * 64 * 2;  // 64 KB

  hipMemsetAsync(facc, 0, (size_t)B_ * C_ * 64 * 2 * sizeof(float), stream);
  conv_main<<<1024, 256, 0, stream>>>((const v2f*)x, wir, wii, facc);
  nonlin_out<<<(B_ * C_) / 4, 256, 0, stream>>>(facc, Anl, Wcm, wrr, wri, pre);
  bn_kernel<<<C_, 128, 0, stream>>>(pre, gam, bet, (float*)d_out);
}

// Round 4
// 550.308 us; speedup vs baseline: 1.7020x; 1.0371x over previous
//
#include <hip/hip_runtime.h>

typedef float v2f __attribute__((ext_vector_type(2)));

#define B_ 64
#define N_ 4096
#define C_ 128
#define W_ 64
#define WIN_ 4033
#define CG 8        // channels per block
#define CHUNK 256   // n per staged chunk
#define STAGE 336   // CHUNK + 80 lookahead (max window read = +319)
#define SROW 337    // odd LDS row stride (f2): bank-pair = (cl + 8*tg + k) mod 16
#define KPAD 4176   // padded w row: kk = k + 64, k in [-64, 4112)

__device__ __forceinline__ v2f pk_fma(v2f a, v2f b, v2f c) {
  v2f d;
  asm("v_pk_fma_f32 %0, %1, %2, %3" : "=v"(d) : "v"(a), "v"(b), "v"(c));
  return d;
}

// Build interleaved, zero-padded weight table w2pad[c][kk] = (wr[c][k], wi[c][k])
__global__ void prep_w(const float* __restrict__ wr, const float* __restrict__ wi,
                       v2f* __restrict__ w2pad) {
  int idx = blockIdx.x * 256 + threadIdx.x;  // exact: C_*KPAD = 2088*256
  int c = idx / KPAD;
  int kk = idx - c * KPAD;
  int k = kk - 64;
  v2f v = {0.f, 0.f};
  if (k >= 0 && k < WIN_) {
    v.x = wr[c * WIN_ + k];
    v.y = wi[c * WIN_ + k];
  }
  w2pad[idx] = v;
}

// Depthwise sliding correlation (complex pair packed) + fused nonlinearity +
// output filter. Grid: 64 b x 16 cg = 1024 blocks, 256 threads; full grid
// co-resident (21.6 KB LDS, <=128 VGPR -> 4 blocks/CU).
// Thread roles: cl = tid&7 (channel, low bits -> LDS bank spread),
// tg = (tid>>3)&7 -> t0 = 8*tg (8 t per thread), np = tid>>6 (n-quarter).
__global__ __launch_bounds__(256, 4) void conv_main(
    const v2f* __restrict__ x2,     // [B][N][C] f2
    const v2f* __restrict__ w2pad,  // [C][KPAD] f2
    const float* __restrict__ Anl,  // [C][2][2]
    const float* __restrict__ Wcm,  // [2][2]
    const float* __restrict__ wor,  // [C][W]
    const float* __restrict__ woi,  // [C][W]
    float* __restrict__ pre) {      // [B][C][2] pre-BN
  __shared__ __attribute__((aligned(16))) v2f wsh[CG * SROW];  // 21.6 KB

  int tid = threadIdx.x;
  int bid = blockIdx.x;
  int bb = bid >> 4;   // consecutive bids = same b, all 16 cg -> L3 line sharing
  int cg = bid & 15;
  int cbase = cg * CG;
  int cl = tid & 7;
  int tg = (tid >> 3) & 7;
  int np = tid >> 6;
  int t0 = tg << 3;
  int nbase = np << 6;

  v2f acc[8];
#pragma unroll
  for (int i = 0; i < 8; i++) acc[i] = (v2f){0.f, 0.f};

  const v2f* xg = x2 + (size_t)bb * N_ * C_ + cbase + cl;
  const v2f* wrow = wsh + cl * SROW;
  const v2f* wsrc = w2pad + (size_t)cbase * KPAD;

  v2f W[16], xA[8], xB[8];

  for (int n0 = 0; n0 < N_; n0 += CHUNK) {
    // preload first x micro-block (global, overlaps barrier + staging)
#pragma unroll
    for (int j = 0; j < 8; j++) xA[j] = xg[(size_t)(n0 + nbase + j) * C_];

    __syncthreads();  // previous chunk's compute done reading wsh
    // stage 8ch x 336 f2 from prebuilt table (coalesced 8B/lane)
    for (int i = tid; i < CG * STAGE; i += 256) {
      int c = i / STAGE;
      int u = i - c * STAGE;
      wsh[c * SROW + u] = wsrc[(size_t)c * KPAD + n0 + u];
    }
    __syncthreads();

    // init 16-f2 register window: W[m] = staged[nbase + 57 - t0 + m]
#pragma unroll
    for (int m = 0; m < 16; m++) W[m] = wrow[nbase + 57 - t0 + m];

#pragma unroll
    for (int blk = 0; blk < 8; ++blk) {
      int nb = nbase + blk * 8;
      const v2f* xv = (blk & 1) ? xB : xA;
      v2f* xo = (blk & 1) ? xA : xB;
      if (blk < 7) {  // prefetch next 8 x
#pragma unroll
        for (int j = 0; j < 8; j++) xo[j] = xg[(size_t)(n0 + nb + 8 + j) * C_];
      }
      // f[t0+i] += x[nb+j] * w[(nb+j) - (t0+i)]; staged idx u = n - t + 64
#pragma unroll
      for (int j = 0; j < 8; j++) {
#pragma unroll
        for (int i = 0; i < 8; i++) {
          acc[i] = pk_fma(xv[j], W[7 + j - i], acc[i]);
        }
      }
      if (blk < 7) {  // slide window by 8 (register-renamed), read 8 new
#pragma unroll
        for (int m = 0; m < 8; m++) W[m] = W[m + 8];
#pragma unroll
        for (int r = 0; r < 8; r++) W[8 + r] = wrow[nb + 73 - t0 + r];
      }
    }
  }

  // ---- reduce n-quarters (np = wave) via LDS, stride 65 ----
  __syncthreads();  // all compute done; reuse wsh
  v2f* fpart = wsh;  // [np*8+cl] rows of 65 f2: max 31*65+63 = 2078 < 2696
#pragma unroll
  for (int i = 0; i < 8; i++) fpart[(np * 8 + cl) * 65 + t0 + i] = acc[i];
  __syncthreads();

  // ---- fused nonlinearity + output filter ----
  int cl2 = tid & 7;
  int tt = tid >> 3;  // 0..31
  int c = cbase + cl2;
  float a00 = Anl[c * 4 + 0], a01 = Anl[c * 4 + 1];
  float a10 = Anl[c * 4 + 2], a11 = Anl[c * 4 + 3];
  float wc00 = Wcm[0], wc01 = Wcm[1], wc10 = Wcm[2], wc11 = Wcm[3];
  float or_ = 0.f, oi_ = 0.f;
#pragma unroll
  for (int h = 0; h < 2; h++) {
    int t = tt + (h << 5);
    v2f f = fpart[(0 * 8 + cl2) * 65 + t] + fpart[(1 * 8 + cl2) * 65 + t] +
            fpart[(2 * 8 + cl2) * 65 + t] + fpart[(3 * 8 + cl2) * 65 + t];
    float ur = a00 * f.x + a01 * f.y;
    float ui = a10 * f.x + a11 * f.y;
    float amp = ur * ur + ui * ui;
    ur *= amp;
    ui *= amp;
    float vr = wc00 * ur + wc01 * ui;
    float vi = wc10 * ur + wc11 * ui;
    or_ += vr * wor[c * 64 + t];
    oi_ += vi * woi[c * 64 + t];
  }
  // reduce over tt within wave (lanes stride 8 share cl2)
  or_ += __shfl_down(or_, 32, 64);
  oi_ += __shfl_down(oi_, 32, 64);
  or_ += __shfl_down(or_, 16, 64);
  oi_ += __shfl_down(oi_, 16, 64);
  or_ += __shfl_down(or_, 8, 64);
  oi_ += __shfl_down(oi_, 8, 64);
  v2f* opart = wsh + 2200;  // disjoint from fpart [0,2080)
  if ((tid & 63) < 8) opart[(tid >> 6) * 8 + cl2] = (v2f){or_, oi_};
  __syncthreads();
  if (tid < 8) {
    v2f r = opart[cl2] + opart[8 + cl2] + opart[16 + cl2] + opart[24 + cl2];
    ((v2f*)pre)[(size_t)bb * C_ + cbase + cl2] = r;
  }
}

// Train-mode BatchNorm1d over (B, comp) per channel. 128 blocks x 128 thr.
__global__ void bn_kernel(const float* __restrict__ pre, const float* __restrict__ gamma,
                          const float* __restrict__ beta, float* __restrict__ out) {
  int c = blockIdx.x, tid = threadIdx.x;
  int b = tid >> 1, comp = tid & 1;
  float v = pre[((size_t)b * C_ + c) * 2 + comp];
  float s = v, s2 = v * v;
#pragma unroll
  for (int d = 32; d > 0; d >>= 1) {
    s += __shfl_down(s, d, 64);
    s2 += __shfl_down(s2, d, 64);
  }
  __shared__ float red[4];
  if ((tid & 63) == 0) {
    red[(tid >> 6) * 2 + 0] = s;
    red[(tid >> 6) * 2 + 1] = s2;
  }
  __syncthreads();
  float sum = red[0] + red[2], sumsq = red[1] + red[3];
  float mean = sum * 0.0078125f;
  float var = sumsq * 0.0078125f - mean * mean;
  float inv = rsqrtf(var + 1e-5f);
  out[((size_t)b * C_ + c) * 2 + comp] = (v - mean) * inv * gamma[c] + beta[c];
}

extern "C" void kernel_launch(void* const* d_in, const int* in_sizes, int n_in,
                              void* d_out, int out_size, void* d_ws, size_t ws_size,
                              hipStream_t stream) {
  (void)in_sizes; (void)n_in; (void)out_size; (void)ws_size;
  const float* x   = (const float*)d_in[0];
  const float* wir = (const float*)d_in[1];
  const float* wii = (const float*)d_in[2];
  const float* Anl = (const float*)d_in[3];
  const float* Wcm = (const float*)d_in[4];
  const float* wrr = (const float*)d_in[5];
  const float* wri = (const float*)d_in[6];
  const float* gam = (const float*)d_in[7];
  const float* bet = (const float*)d_in[8];

  v2f* w2pad = (v2f*)d_ws;                                             // 4.28 MB
  float* pre = (float*)((char*)d_ws + (size_t)C_ * KPAD * sizeof(v2f));  // 64 KB

  prep_w<<<(C_ * KPAD) / 256, 256, 0, stream>>>(wir, wii, w2pad);
  conv_main<<<B_ * (C_ / CG), 256, 0, stream>>>((const v2f*)x, w2pad, Anl, Wcm,
                                                wrr, wri, pre);
  bn_kernel<<<C_, 128, 0, stream>>>(pre, gam, bet, (float*)d_out);
}